// Round 1
// baseline (718.896 us; speedup 1.0000x reference)
//
#include <hip/hip_runtime.h>
#include <hip/hip_bf16.h>

#define NEG_SLOPE 0.2f

// ---------------------------------------------------------------------------
// GEMM: HP[h][n][f] = sum_k X[n][k] * W[h][k][f]    (K=256, F=64, H=4)
// fp32 vector GEMM (no fp32 MFMA on CDNA4). 128x64 tile, 8x4 micro-tile.
// ---------------------------------------------------------------------------
__global__ __launch_bounds__(256) void gemm_hp_k(
    const float* __restrict__ X,   // [n, 256]
    const float* __restrict__ W,   // [4, 256, 64]
    float* __restrict__ HP,        // [4, n, 64]
    int n)
{
    const int h    = blockIdx.y;
    const int row0 = blockIdx.x * 128;
    __shared__ float As[128][65];   // +1 pad
    __shared__ float Bs[64][68];    // +4 pad (keeps float4 alignment)

    const int t  = threadIdx.x;       // 0..255
    const int ty = t >> 4;            // 0..15 -> rows ty*8..ty*8+7
    const int tx = t & 15;            // 0..15 -> cols tx*4..tx*4+3
    const float* Wh = W + (size_t)h * 256 * 64;

    float acc[8][4] = {};

    for (int k0 = 0; k0 < 256; k0 += 64) {
        __syncthreads();
        // load A tile: 128x64 floats, guarded rows -> zeros
        #pragma unroll
        for (int i = 0; i < 8; ++i) {
            int linear = t + i * 256;         // 0..2047
            int r  = linear >> 4;             // 0..127
            int c4 = linear & 15;             // 0..15
            int gr = row0 + r;
            float4 v = make_float4(0.f, 0.f, 0.f, 0.f);
            if (gr < n) v = *(const float4*)(X + (size_t)gr * 256 + k0 + c4 * 4);
            As[r][c4 * 4 + 0] = v.x; As[r][c4 * 4 + 1] = v.y;
            As[r][c4 * 4 + 2] = v.z; As[r][c4 * 4 + 3] = v.w;
        }
        // load B tile: 64x64 floats (contiguous in W)
        #pragma unroll
        for (int i = 0; i < 4; ++i) {
            int linear = t + i * 256;         // 0..1023
            int r  = linear >> 4;             // 0..63
            int c4 = linear & 15;
            float4 v = *(const float4*)(Wh + (size_t)(k0 + r) * 64 + c4 * 4);
            *(float4*)&Bs[r][c4 * 4] = v;
        }
        __syncthreads();

        #pragma unroll 16
        for (int kk = 0; kk < 64; ++kk) {
            float b[4];
            *(float4*)b = *(const float4*)&Bs[kk][tx * 4];
            #pragma unroll
            for (int i = 0; i < 8; ++i) {
                float a = As[ty * 8 + i][kk];
                acc[i][0] += a * b[0];
                acc[i][1] += a * b[1];
                acc[i][2] += a * b[2];
                acc[i][3] += a * b[3];
            }
        }
    }

    #pragma unroll
    for (int i = 0; i < 8; ++i) {
        int gr = row0 + ty * 8 + i;
        if (gr < n) {
            float4 v = make_float4(acc[i][0], acc[i][1], acc[i][2], acc[i][3]);
            *(float4*)(HP + ((size_t)h * n + gr) * 64 + tx * 4) = v;
        }
    }
}

// ---------------------------------------------------------------------------
// attention projections: as_[n][h] = dot(HP[h][n][:], a_src[h]);  same for trg
// ---------------------------------------------------------------------------
__global__ __launch_bounds__(256) void attn_proj_k(
    const float* __restrict__ HP, const float* __restrict__ a_src,
    const float* __restrict__ a_trg,
    float* __restrict__ as_, float* __restrict__ at_, int n)
{
    const int h  = blockIdx.y;
    const int nn = blockIdx.x * 256 + threadIdx.x;
    if (nn >= n) return;
    const float* row = HP + ((size_t)h * n + nn) * 64;
    const float* pa  = a_src + h * 64;
    const float* pb  = a_trg + h * 64;
    float s = 0.f, u = 0.f;
    #pragma unroll
    for (int k4 = 0; k4 < 16; ++k4) {
        float4 v = *(const float4*)(row + k4 * 4);
        float4 p = *(const float4*)(pa + k4 * 4);
        float4 q = *(const float4*)(pb + k4 * 4);
        s += v.x * p.x + v.y * p.y + v.z * p.z + v.w * p.w;
        u += v.x * q.x + v.y * q.y + v.z * q.z + v.w * q.w;
    }
    as_[nn * 4 + h] = s;
    at_[nn * 4 + h] = u;
}

// ---------------------------------------------------------------------------
// CSR build: histogram -> scan -> scatter (counting sort of edges by trg)
// ---------------------------------------------------------------------------
__global__ void hist_k(const int* __restrict__ trg, int* __restrict__ counts,
                       int* __restrict__ ranks, int E)
{
    int e = blockIdx.x * blockDim.x + threadIdx.x;
    if (e < E) ranks[e] = atomicAdd(&counts[trg[e]], 1);
}

__global__ __launch_bounds__(1024) void scan_k(const int* __restrict__ counts,
                                               int* __restrict__ starts, int n)
{
    const int T = 1024;
    int t = threadIdx.x;
    int chunk = (n + T - 1) / T;
    int beg = t * chunk;
    int end = min(beg + chunk, n);
    int sum = 0;
    for (int i = beg; i < end; ++i) sum += counts[i];
    __shared__ int lds[T];
    lds[t] = sum;
    __syncthreads();
    for (int off = 1; off < T; off <<= 1) {
        int v = (t >= off) ? lds[t - off] : 0;
        __syncthreads();
        lds[t] += v;
        __syncthreads();
    }
    int run = lds[t] - sum;   // exclusive prefix of this thread's chunk
    for (int i = beg; i < end; ++i) { starts[i] = run; run += counts[i]; }
    if (t == T - 1) starts[n] = lds[T - 1];
}

__global__ void scatter_k(const int* __restrict__ trg, const int* __restrict__ starts,
                          const int* __restrict__ ranks, int* __restrict__ sorted, int E)
{
    int e = blockIdx.x * blockDim.x + threadIdx.x;
    if (e < E) sorted[starts[trg[e]] + ranks[e]] = e;
}

// ---------------------------------------------------------------------------
// per-node aggregation: out[v,h,f] = (sum_e p_e * HP[h][src_e][f]) / (sum_e p_e + 1e-16)
// p_e = exp(leaky_relu(as_[src_e,h] + at_[v,h]))   (global-max shift cancels)
// LAYER 0: writes elu(val) to buf[v*256 + h*64 + f]
// LAYER 1: writes head-mean to out[v*64 + f]
// ---------------------------------------------------------------------------
template<int LAYER>
__global__ __launch_bounds__(256) void aggregate_k(
    const float* __restrict__ HP, const float* __restrict__ as_,
    const float* __restrict__ at_, const int* __restrict__ src,
    const int* __restrict__ starts, const int* __restrict__ sorted,
    float* __restrict__ out, int n)
{
    const int v = blockIdx.x;
    const int t = threadIdx.x;      // 256
    const int h = t >> 6;           // 0..3
    const int f = t & 63;           // 0..63

    const int s0 = starts[v];
    const int s1 = starts[v + 1];
    const float atv = at_[v * 4 + h];
    const float* hpb = HP + ((size_t)h * n) * 64 + f;

    __shared__ int   sh_s[64];
    __shared__ float sh_p[4][64];

    float acc = 0.f, den = 0.f;

    for (int base = s0; base < s1; base += 64) {
        int m = min(64, s1 - base);
        __syncthreads();
        if (t < m) {
            int e = sorted[base + t];
            sh_s[t] = src[e];
        }
        __syncthreads();
        if (f < m) {   // thread (h, i=f) computes p for edge i, head h
            float e_ = as_[sh_s[f] * 4 + h] + atv;
            e_ = (e_ > 0.f) ? e_ : NEG_SLOPE * e_;
            sh_p[h][f] = expf(e_);
        }
        __syncthreads();
        #pragma unroll 4
        for (int i = 0; i < m; ++i) {
            float p = sh_p[h][i];
            den += p;
            acc += p * hpb[(size_t)sh_s[i] * 64];
        }
    }

    float val = acc / (den + 1e-16f);

    if (LAYER == 0) {
        // elu fused
        val = (val > 0.f) ? val : expm1f(val);
        out[(size_t)v * 256 + h * 64 + f] = val;
    } else {
        __shared__ float red[256];
        red[t] = val;
        __syncthreads();
        if (t < 64)
            out[(size_t)v * 64 + t] =
                0.25f * (red[t] + red[64 + t] + red[128 + t] + red[192 + t]);
    }
}

// ---------------------------------------------------------------------------
// final: logits = [out_u | out_t] @ fc_w + fc_b ; log_softmax over 16
// 16 threads per node; shuffle reductions with width 16.
// ---------------------------------------------------------------------------
__global__ __launch_bounds__(256) void final_k(
    const float* __restrict__ out_u, const float* __restrict__ out_t,
    const float* __restrict__ fcw, const float* __restrict__ fcb,
    float* __restrict__ out, int nret)
{
    int gid = blockIdx.x * blockDim.x + threadIdx.x;
    int nn = gid >> 4;
    int j  = gid & 15;
    if (nn >= nret) return;
    const float* ru = out_u + (size_t)nn * 64;
    const float* rt = out_t + (size_t)nn * 64;
    float acc = fcb[j];
    #pragma unroll 8
    for (int k = 0; k < 64; ++k) acc += ru[k] * fcw[k * 16 + j];
    #pragma unroll 8
    for (int k = 0; k < 64; ++k) acc += rt[k] * fcw[(64 + k) * 16 + j];

    float m = acc;
    for (int off = 8; off; off >>= 1) m = fmaxf(m, __shfl_xor(m, off, 16));
    float ex = expf(acc - m);
    float s = ex;
    for (int off = 8; off; off >>= 1) s += __shfl_xor(s, off, 16);
    out[(size_t)nn * 16 + j] = acc - m - logf(s);
}

// ---------------------------------------------------------------------------
extern "C" void kernel_launch(void* const* d_in, const int* in_sizes, int n_in,
                              void* d_out, int out_size, void* d_ws, size_t ws_size,
                              hipStream_t stream)
{
    const int N = in_sizes[0] / 256;     // 20000
    const int E = in_sizes[2];           // 320000
    const int NRET = out_size / 16;      // 20000

    const float* emb[2] = { (const float*)d_in[0], (const float*)d_in[1] };
    const int*   src[2] = { (const int*)d_in[2], (const int*)d_in[4] };
    const int*   trg[2] = { (const int*)d_in[3], (const int*)d_in[5] };
    const float* fcw = (const float*)d_in[18];
    const float* fcb = (const float*)d_in[19];

    // workspace layout
    float* hp   = (float*)d_ws;                       // 4*N*64
    float* buf  = hp + (size_t)4 * N * 64;            // 4*N*64
    float* as_  = buf + (size_t)4 * N * 64;           // N*4
    float* at_  = as_ + (size_t)N * 4;                // N*4
    float* out_s[2];
    out_s[0] = at_ + (size_t)N * 4;                   // N*64
    out_s[1] = out_s[0] + (size_t)N * 64;             // N*64
    int* starts = (int*)(out_s[1] + (size_t)N * 64);  // N+1
    int* counts = starts + (N + 1);                   // N
    int* ranks  = counts + N;                         // E
    int* sorted = ranks + E;                          // E

    const int EB = (E + 255) / 256;

    for (int side = 0; side < 2; ++side) {
        const float* w0  = (const float*)d_in[6 + side * 6 + 0];
        const float* as0 = (const float*)d_in[6 + side * 6 + 1];
        const float* at0 = (const float*)d_in[6 + side * 6 + 2];
        const float* w1  = (const float*)d_in[6 + side * 6 + 3];
        const float* as1 = (const float*)d_in[6 + side * 6 + 4];
        const float* at1 = (const float*)d_in[6 + side * 6 + 5];

        // CSR build (same graph for both layers of this side)
        hipMemsetAsync(counts, 0, (size_t)N * sizeof(int), stream);
        hist_k<<<EB, 256, 0, stream>>>(trg[side], counts, ranks, E);
        scan_k<<<1, 1024, 0, stream>>>(counts, starts, N);
        scatter_k<<<EB, 256, 0, stream>>>(trg[side], starts, ranks, sorted, E);

        // layer 0
        gemm_hp_k<<<dim3((N + 127) / 128, 4), 256, 0, stream>>>(emb[side], w0, hp, N);
        attn_proj_k<<<dim3((N + 255) / 256, 4), 256, 0, stream>>>(hp, as0, at0, as_, at_, N);
        aggregate_k<0><<<N, 256, 0, stream>>>(hp, as_, at_, src[side], starts, sorted, buf, N);

        // layer 1
        gemm_hp_k<<<dim3((N + 127) / 128, 4), 256, 0, stream>>>(buf, w1, hp, N);
        attn_proj_k<<<dim3((N + 255) / 256, 4), 256, 0, stream>>>(hp, as1, at1, as_, at_, N);
        aggregate_k<1><<<N, 256, 0, stream>>>(hp, as_, at_, src[side], starts, sorted, out_s[side], N);
    }

    final_k<<<(NRET * 16 + 255) / 256, 256, 0, stream>>>(out_s[0], out_s[1], fcw, fcb,
                                                         (float*)d_out, NRET);
}